// Round 6
// baseline (1001.420 us; speedup 1.0000x reference)
//
#include <hip/hip_runtime.h>

#define IN_DIM 128
#define HID 256
#define OUTD 64

typedef __attribute__((ext_vector_type(8))) short bf16x8;
typedef __attribute__((ext_vector_type(4))) float f32x4;
typedef __attribute__((ext_vector_type(8))) unsigned short ushort8v;

// ---- bf16 helpers (RNE) ----
__device__ __forceinline__ unsigned short f2bf(float x) {
    unsigned int u = __float_as_uint(x);
    unsigned int r = (u + 0x7fffu + ((u >> 16) & 1u)) >> 16;
    return (unsigned short)r;
}
__device__ __forceinline__ float bf2f(unsigned short b) {
    return __uint_as_float(((unsigned int)b) << 16);
}

// ================= bucket-sort CSR build (no scattered global atomics) =================
// Buckets of 256 nodes: bucket(v) = v>>8. NBK = ceil(N/256) = 391 for N=100000. NBK <= 512.

// Pass A: coarse bucket histograms (src-bucket and dst-bucket counts) via LDS.
__global__ __launch_bounds__(256) void k_bucketA(const int* __restrict__ src,
                                                 const int* __restrict__ dst,
                                                 int* __restrict__ bktS, int* __restrict__ bktD,
                                                 int E, int NBK) {
    __shared__ int hS[512], hD[512];
    int t = threadIdx.x;
    for (int j = t; j < 512; j += 256) { hS[j] = 0; hD[j] = 0; }
    __syncthreads();
    for (int e = blockIdx.x * 256 + t; e < E; e += gridDim.x * 256) {
        atomicAdd(&hS[src[e] >> 8], 1);
        atomicAdd(&hD[dst[e] >> 8], 1);
    }
    __syncthreads();
    for (int j = t; j < NBK; j += 256) {
        if (hS[j]) atomicAdd(&bktS[j], hS[j]);
        if (hD[j]) atomicAdd(&bktD[j], hD[j]);
    }
}

// Scan both bucket-count arrays; init cursors; eoff[N]=E.
__global__ __launch_bounds__(512) void k_bscan(const int* __restrict__ bktS,
                                               const int* __restrict__ bktD,
                                               int* __restrict__ sOff, int* __restrict__ dOff,
                                               int* __restrict__ curS, int* __restrict__ curD,
                                               int* __restrict__ eoff,
                                               int N, int E, int NBK) {
    __shared__ int sS[512], sD[512];
    int t = threadIdx.x;
    int vS = (t < NBK) ? bktS[t] : 0;
    int vD = (t < NBK) ? bktD[t] : 0;
    sS[t] = vS; sD[t] = vD;
    __syncthreads();
    for (int o = 1; o < 512; o <<= 1) {
        int xS = (t >= o) ? sS[t - o] : 0;
        int xD = (t >= o) ? sD[t - o] : 0;
        __syncthreads();
        sS[t] += xS; sD[t] += xD;
        __syncthreads();
    }
    if (t < NBK) {
        int eS = sS[t] - vS, eD = sD[t] - vD;
        sOff[t] = eS; dOff[t] = eD;
        curS[t] = eS; curD[t] = eD;
    }
    if (t == 0) { sOff[NBK] = E; dOff[NBK] = E; eoff[N] = E; }
}

// Pass B: scatter edges into dst buckets (packed (dloc<<17)|src) and src-local ids into src buckets.
__global__ __launch_bounds__(256) void k_bucketB(const int* __restrict__ src,
                                                 const int* __restrict__ dst,
                                                 int* __restrict__ curS, int* __restrict__ curD,
                                                 unsigned int* __restrict__ dpairs,
                                                 unsigned char* __restrict__ sloc, int E) {
    int e = blockIdx.x * 256 + threadIdx.x;
    if (e >= E) return;
    int s = src[e], d = dst[e];
    int pD = atomicAdd(&curD[d >> 8], 1);
    dpairs[pD] = ((unsigned int)(d & 255) << 17) | (unsigned int)s;
    int pS = atomicAdd(&curS[s >> 8], 1);
    sloc[pS] = (unsigned char)(s & 255);
}

// Pass C: per dst-bucket: fine histogram -> nd + eoff, then place esrc via LDS cursors.
__global__ __launch_bounds__(256) void k_bucketC(const unsigned int* __restrict__ dpairs,
                                                 const int* __restrict__ dOff,
                                                 int* __restrict__ eoff,
                                                 int* __restrict__ esrc,
                                                 float* __restrict__ nd,
                                                 int N) {
    __shared__ int hist[256], sc[256], cur[256];
    int b = blockIdx.x, t = threadIdx.x;
    int base = dOff[b], end = dOff[b + 1];
    hist[t] = 0;
    __syncthreads();
    for (int i = base + t; i < end; i += 256)
        atomicAdd(&hist[dpairs[i] >> 17], 1);
    __syncthreads();
    int cnt = hist[t];
    int v = b * 256 + t;
    if (v < N) nd[v] = rsqrtf((float)max(cnt, 1));
    sc[t] = cnt;
    __syncthreads();
    for (int o = 1; o < 256; o <<= 1) {
        int x = (t >= o) ? sc[t - o] : 0;
        __syncthreads();
        sc[t] += x;
        __syncthreads();
    }
    int excl = sc[t] - cnt;
    if (v < N) eoff[v] = base + excl;
    cur[t] = excl;
    __syncthreads();
    for (int i = base + t; i < end; i += 256) {
        unsigned int pk = dpairs[i];
        int pos = atomicAdd(&cur[pk >> 17], 1);
        esrc[base + pos] = (int)(pk & 0x1FFFFu);
    }
}

// Pass C': per src-bucket: fine histogram -> ns.
__global__ __launch_bounds__(256) void k_bucketCs(const unsigned char* __restrict__ sloc,
                                                  const int* __restrict__ sOff,
                                                  float* __restrict__ ns,
                                                  int N) {
    __shared__ int hist[256];
    int b = blockIdx.x, t = threadIdx.x;
    int base = sOff[b], end = sOff[b + 1];
    hist[t] = 0;
    __syncthreads();
    for (int i = base + t; i < end; i += 256)
        atomicAdd(&hist[sloc[i]], 1);
    __syncthreads();
    int v = b * 256 + t;
    if (v < N) ns[v] = rsqrtf((float)max(hist[t], 1));
}

// ---------------- h pre-scale + bf16 convert: hb[v][d] = bf16(h[v][d]*ns[v]) ----------------
__global__ void k_hconv(const float* __restrict__ h, const float* __restrict__ ns,
                        unsigned short* __restrict__ hb, int total4) {
    int i = blockIdx.x * 256 + threadIdx.x;  // one float4 per thread
    if (i >= total4) return;
    int node = i >> 5;  // 32 float4 per row of 128
    float nsv = ns[node];
    float4 v = ((const float4*)h)[i];
    ushort4 o;
    o.x = f2bf(v.x * nsv);
    o.y = f2bf(v.y * nsv);
    o.z = f2bf(v.z * nsv);
    o.w = f2bf(v.w * nsv);
    ((ushort4*)hb)[i] = o;
}

// ---------------- W prep: transpose + bf16 ----------------
__global__ void k_wprep(const float* __restrict__ W1, const float* __restrict__ W2,
                        unsigned short* __restrict__ Wt1, unsigned short* __restrict__ Wt2) {
    int t = blockIdx.x * 256 + threadIdx.x;
    if (t < IN_DIM * HID) {
        int k = t & (IN_DIM - 1), n = t >> 7;
        Wt1[(size_t)n * IN_DIM + k] = f2bf(W1[(size_t)k * HID + n]);
    }
    if (t < HID * OUTD) {
        int k = t & (HID - 1), n = t >> 8;
        Wt2[(size_t)n * HID + k] = f2bf(W2[(size_t)k * OUTD + n]);
    }
}

// ---------------- SPMM1: bf16 gather of hb (pre-scaled), out xb bf16 [N][128] ----------------
__global__ __launch_bounds__(256) void k_spmm1(const unsigned short* __restrict__ hb,
                                               const int* __restrict__ eoff,
                                               const int* __restrict__ esrc,
                                               const float* __restrict__ nd,
                                               unsigned short* __restrict__ xb, int N) {
    int wid = threadIdx.x >> 6;
    int v = blockIdx.x * 4 + wid;
    if (v >= N) return;
    int l = threadIdx.x & 63;
    int c = l & 15, el = l >> 4;
    int s0 = eoff[v], s1 = eoff[v + 1];

    float a0[8] = {0.f, 0.f, 0.f, 0.f, 0.f, 0.f, 0.f, 0.f};
    float a1[8] = {0.f, 0.f, 0.f, 0.f, 0.f, 0.f, 0.f, 0.f};
    int i = s0 + el;
    for (; i + 4 < s1; i += 8) {
        int sA = esrc[i], sB = esrc[i + 4];
        ushort8v uA = *(const ushort8v*)(hb + (size_t)sA * IN_DIM + c * 8);
        ushort8v uB = *(const ushort8v*)(hb + (size_t)sB * IN_DIM + c * 8);
#pragma unroll
        for (int k = 0; k < 8; ++k) {
            a0[k] += bf2f((unsigned short)uA[k]);
            a1[k] += bf2f((unsigned short)uB[k]);
        }
    }
    for (; i < s1; i += 4) {
        int sA = esrc[i];
        ushort8v uA = *(const ushort8v*)(hb + (size_t)sA * IN_DIM + c * 8);
#pragma unroll
        for (int k = 0; k < 8; ++k) a0[k] += bf2f((unsigned short)uA[k]);
    }
    float s[8];
#pragma unroll
    for (int k = 0; k < 8; ++k) {
        float x = a0[k] + a1[k];
        x += __shfl_xor(x, 16);
        x += __shfl_xor(x, 32);
        s[k] = x;
    }
    if (el == 0) {
        float ndv = nd[v];
        uint4 o;
        unsigned int* op = (unsigned int*)&o;
#pragma unroll
        for (int k = 0; k < 4; ++k) {
            unsigned int lo = f2bf(s[2 * k] * ndv);
            unsigned int hi = f2bf(s[2 * k + 1] * ndv);
            op[k] = lo | (hi << 16);
        }
        *(uint4*)(xb + (size_t)v * IN_DIM + c * 8) = o;
    }
}

// ---------------- MFMA GEMM: C = A(M x K,bf16) * Bt(BN x K,bf16)^T ----------------
template <int EPI>
__global__ __launch_bounds__(256) void k_mgemm(const unsigned short* __restrict__ A,
                                               const unsigned short* __restrict__ Bt,
                                               const float* __restrict__ b1,
                                               const float* __restrict__ p,
                                               const float* __restrict__ ns,
                                               unsigned short* __restrict__ outp,
                                               int M) {
    constexpr int BM = (EPI == 1) ? 64 : 256;
    constexpr int BN = (EPI == 1) ? 256 : 64;
    constexpr int K = (EPI == 1) ? 128 : 256;
    constexpr int OUT_LD = (EPI == 1) ? 256 : 64;
    __shared__ unsigned short As[BM * 64];
    __shared__ unsigned short Bs[BN * 64];
    const int t = threadIdx.x, w = t >> 6, l = t & 63;
    const int row0 = blockIdx.x * BM;
    const int wm0 = (EPI == 1) ? 0 : w * 64;
    const int wn0 = (EPI == 1) ? w * 64 : 0;
    const int lr = l & 15, lk = (l >> 4) * 8, lg = l >> 4;

    f32x4 acc[4][4] = {};

    for (int k0 = 0; k0 < K; k0 += 64) {
#pragma unroll
        for (int q = 0; q < BM / 32; ++q) {
            int chunk = w * (BM / 32) + q;
            int gr = row0 + chunk * 8 + (l >> 3);
            if (gr > M - 1) gr = M - 1;
            const unsigned short* gp = A + (size_t)gr * K + k0 + (l & 7) * 8;
            __builtin_amdgcn_global_load_lds((const __attribute__((address_space(1))) void*)gp,
                                             (__attribute__((address_space(3))) void*)&As[chunk * 512], 16, 0, 0);
        }
#pragma unroll
        for (int q = 0; q < BN / 32; ++q) {
            int chunk = w * (BN / 32) + q;
            int r = chunk * 8 + (l >> 3);
            const unsigned short* gp = Bt + (size_t)r * K + k0 + (l & 7) * 8;
            __builtin_amdgcn_global_load_lds((const __attribute__((address_space(1))) void*)gp,
                                             (__attribute__((address_space(3))) void*)&Bs[chunk * 512], 16, 0, 0);
        }
        __syncthreads();

#pragma unroll
        for (int kk = 0; kk < 2; ++kk) {
            bf16x8 a[4], b[4];
#pragma unroll
            for (int m = 0; m < 4; ++m)
                a[m] = *(const bf16x8*)&As[(wm0 + m * 16 + lr) * 64 + kk * 32 + lk];
#pragma unroll
            for (int n = 0; n < 4; ++n)
                b[n] = *(const bf16x8*)&Bs[(wn0 + n * 16 + lr) * 64 + kk * 32 + lk];
#pragma unroll
            for (int m = 0; m < 4; ++m)
#pragma unroll
                for (int n = 0; n < 4; ++n)
                    acc[m][n] = __builtin_amdgcn_mfma_f32_16x16x32_bf16(a[m], b[n], acc[m][n], 0, 0, 0);
        }
        __syncthreads();
    }

#pragma unroll
    for (int n = 0; n < 4; ++n) {
        int col = wn0 + n * 16 + lr;
        float bb = 0.f, pp = 1.f;
        if (EPI == 1) {
            bb = b1[col];
            pp = fminf(fmaxf(p[col], 0.f), 1.f);
        }
#pragma unroll
        for (int m = 0; m < 4; ++m) {
#pragma unroll
            for (int j = 0; j < 4; ++j) {
                int row = row0 + wm0 + m * 16 + lg * 4 + j;
                if (row < M) {
                    float v = acc[m][n][j];
                    if (EPI == 1) {
                        v = fmaxf(v + bb, 0.f) * pp;
                    } else {
                        v *= ns[row];
                    }
                    outp[(size_t)row * OUT_LD + col] = f2bf(v);
                }
            }
        }
    }
}

// ---------------- SPMM2: bf16 gather of y, out fp32 ----------------
__global__ __launch_bounds__(256) void k_spmm2(const unsigned short* __restrict__ ybf,
                                               const int* __restrict__ eoff,
                                               const int* __restrict__ esrc,
                                               const float* __restrict__ nd,
                                               const float* __restrict__ b2,
                                               float* __restrict__ out, int N) {
    int wid = threadIdx.x >> 6;
    int v = blockIdx.x * 4 + wid;
    if (v >= N) return;
    int l = threadIdx.x & 63;
    int c = l & 15, el = l >> 4;
    int s0 = eoff[v], s1 = eoff[v + 1];

    float ax0 = 0.f, ay0 = 0.f, az0 = 0.f, aw0 = 0.f;
    float ax1 = 0.f, ay1 = 0.f, az1 = 0.f, aw1 = 0.f;
    int i = s0 + el;
    for (; i + 4 < s1; i += 8) {
        int sA = esrc[i], sB = esrc[i + 4];
        ushort4 uA = *(const ushort4*)(ybf + (size_t)sA * OUTD + c * 4);
        ushort4 uB = *(const ushort4*)(ybf + (size_t)sB * OUTD + c * 4);
        ax0 += bf2f(uA.x); ay0 += bf2f(uA.y); az0 += bf2f(uA.z); aw0 += bf2f(uA.w);
        ax1 += bf2f(uB.x); ay1 += bf2f(uB.y); az1 += bf2f(uB.z); aw1 += bf2f(uB.w);
    }
    for (; i < s1; i += 4) {
        ushort4 u = *(const ushort4*)(ybf + (size_t)esrc[i] * OUTD + c * 4);
        ax0 += bf2f(u.x); ay0 += bf2f(u.y); az0 += bf2f(u.z); aw0 += bf2f(u.w);
    }
    float ax = ax0 + ax1, ay = ay0 + ay1, az = az0 + az1, aw = aw0 + aw1;
    ax += __shfl_xor(ax, 16); ax += __shfl_xor(ax, 32);
    ay += __shfl_xor(ay, 16); ay += __shfl_xor(ay, 32);
    az += __shfl_xor(az, 16); az += __shfl_xor(az, 32);
    aw += __shfl_xor(aw, 16); aw += __shfl_xor(aw, 32);
    if (l < 16) {
        float ndv = nd[v];
        float4 bb = *(const float4*)(b2 + c * 4);
        float4 o;
        o.x = ax * ndv + bb.x;
        o.y = ay * ndv + bb.y;
        o.z = az * ndv + bb.z;
        o.w = aw * ndv + bb.w;
        *(float4*)(out + (size_t)v * OUTD + c * 4) = o;
    }
}

extern "C" void kernel_launch(void* const* d_in, const int* in_sizes, int n_in,
                              void* d_out, int out_size, void* d_ws, size_t ws_size,
                              hipStream_t stream) {
    const float* h  = (const float*)d_in[0];
    const float* W1 = (const float*)d_in[1];
    const float* b1 = (const float*)d_in[2];
    const float* W2 = (const float*)d_in[3];
    const float* b2 = (const float*)d_in[4];
    const float* p  = (const float*)d_in[5];
    const int* src  = (const int*)d_in[6];
    const int* dst  = (const int*)d_in[7];

    const int N = in_sizes[0] / IN_DIM;
    const int E = in_sizes[6];
    const int NBK = (N + 255) >> 8;  // 391 for N=100000 (<= 512)
    float* out = (float*)d_out;

    char* ws = (char*)d_ws;
    size_t off = 0;
    auto alloc = [&](size_t bytes) -> void* {
        void* ptr = ws + off;
        off = (off + bytes + 255) & ~(size_t)255;
        return ptr;
    };
    int* bktS = (int*)alloc(512 * 4);
    int* bktD = (int*)alloc(512 * 4);
    size_t zero_span = off;  // only bucket counters need zeroing
    int* curS = (int*)alloc(512 * 4);
    int* curD = (int*)alloc(512 * 4);
    int* sOff = (int*)alloc(513 * 4);
    int* dOff = (int*)alloc(513 * 4);
    int* eoff = (int*)alloc((size_t)(N + 1) * 4);
    int* esrc = (int*)alloc((size_t)E * 4);
    float* ns = (float*)alloc((size_t)N * 4);
    float* nd = (float*)alloc((size_t)N * 4);
    unsigned short* hb  = (unsigned short*)alloc((size_t)N * IN_DIM * 2);  // 25.6 MB
    unsigned short* xb  = (unsigned short*)alloc((size_t)N * IN_DIM * 2);  // 25.6 MB
    unsigned short* hid = (unsigned short*)alloc((size_t)N * HID * 2);     // 51.2 MB
    unsigned short* Wt1 = (unsigned short*)alloc((size_t)HID * IN_DIM * 2);
    unsigned short* Wt2 = (unsigned short*)alloc((size_t)OUTD * HID * 2);
    unsigned short* ybf = xb;  // xb dead after GEMM1
    // dpairs/sloc overlay the hid region (dead until GEMM1 writes it)
    unsigned int* dpairs = (unsigned int*)hid;                 // E*4 = 6.4 MB
    unsigned char* sloc  = (unsigned char*)hid + (size_t)E * 4; // E*1 = 1.6 MB

    hipMemsetAsync(d_ws, 0, zero_span, stream);

    int tpb = 256;
    k_bucketA<<<128, 256, 0, stream>>>(src, dst, bktS, bktD, E, NBK);
    k_bscan<<<1, 512, 0, stream>>>(bktS, bktD, sOff, dOff, curS, curD, eoff, N, E, NBK);
    k_bucketB<<<(E + tpb - 1) / tpb, tpb, 0, stream>>>(src, dst, curS, curD, dpairs, sloc, E);
    k_bucketC<<<NBK, 256, 0, stream>>>(dpairs, dOff, eoff, esrc, nd, N);
    k_bucketCs<<<NBK, 256, 0, stream>>>(sloc, sOff, ns, N);

    int total4 = N * (IN_DIM / 4);
    k_hconv<<<(total4 + tpb - 1) / tpb, tpb, 0, stream>>>(h, ns, hb, total4);

    k_wprep<<<(IN_DIM * HID + 255) / 256, 256, 0, stream>>>(W1, W2, Wt1, Wt2);

    k_spmm1<<<(N + 3) / 4, 256, 0, stream>>>(hb, eoff, esrc, nd, xb, N);

    k_mgemm<1><<<(N + 63) / 64, 256, 0, stream>>>(xb, Wt1, b1, p, nullptr, hid, N);

    k_mgemm<2><<<(N + 255) / 256, 256, 0, stream>>>(hid, Wt2, nullptr, nullptr, ns, ybf, N);

    k_spmm2<<<(N + 3) / 4, 256, 0, stream>>>(ybf, eoff, esrc, nd, b2, out, N);
}

// Round 7
// 426.535 us; speedup vs baseline: 2.3478x; 2.3478x over previous
//
#include <hip/hip_runtime.h>

#define IN_DIM 128
#define HID 256
#define OUTD 64
#define NB 256  // build blocks

typedef __attribute__((ext_vector_type(8))) short bf16x8;
typedef __attribute__((ext_vector_type(4))) float f32x4;
typedef __attribute__((ext_vector_type(8))) unsigned short ushort8v;

// ---- bf16 helpers (RNE) ----
__device__ __forceinline__ unsigned short f2bf(float x) {
    unsigned int u = __float_as_uint(x);
    unsigned int r = (u + 0x7fffu + ((u >> 16) & 1u)) >> 16;
    return (unsigned short)r;
}
__device__ __forceinline__ float bf2f(unsigned short b) {
    return __uint_as_float(((unsigned int)b) << 16);
}

// ================= atomic-chain-free bucket-sort CSR build =================
// Buckets of 256 nodes: bucket(v) = v>>8. NBK = ceil(N/256) <= 512.
// part arrays layout: part[bucket * NB + block].

// Pass A: per-block LDS histograms over a chunk, written non-atomically.
__global__ __launch_bounds__(256) void k_bucketA(const int* __restrict__ src,
                                                 const int* __restrict__ dst,
                                                 int* __restrict__ partS, int* __restrict__ partD,
                                                 int E, int NBK) {
    __shared__ int hS[512], hD[512];
    int b = blockIdx.x, t = threadIdx.x;
    for (int j = t; j < 512; j += 256) { hS[j] = 0; hD[j] = 0; }
    __syncthreads();
    int chunk = (E + NB - 1) / NB;
    int e0 = b * chunk, e1 = min(E, e0 + chunk);
    for (int e = e0 + t; e < e1; e += 256) {
        atomicAdd(&hS[src[e] >> 8], 1);
        atomicAdd(&hD[dst[e] >> 8], 1);
    }
    __syncthreads();
    for (int j = t; j < NBK; j += 256) {
        partS[j * NB + b] = hS[j];
        partD[j * NB + b] = hD[j];
    }
}

// One-block scan: bucket totals -> cross-bucket exclusive scan -> per-block absolute bases (in place).
__global__ __launch_bounds__(512) void k_bscan2(int* __restrict__ partS, int* __restrict__ partD,
                                                int* __restrict__ sOff, int* __restrict__ dOff,
                                                int* __restrict__ eoff,
                                                int N, int E, int NBK) {
    __shared__ int sS[512], sD[512];
    int t = threadIdx.x;
    int totS = 0, totD = 0;
    if (t < NBK) {
        for (int b = 0; b < NB; ++b) { totS += partS[t * NB + b]; totD += partD[t * NB + b]; }
    }
    sS[t] = totS; sD[t] = totD;
    __syncthreads();
    for (int o = 1; o < 512; o <<= 1) {
        int xS = (t >= o) ? sS[t - o] : 0;
        int xD = (t >= o) ? sD[t - o] : 0;
        __syncthreads();
        sS[t] += xS; sD[t] += xD;
        __syncthreads();
    }
    if (t < NBK) {
        int runS = sS[t] - totS, runD = sD[t] - totD;
        sOff[t] = runS; dOff[t] = runD;
        for (int b = 0; b < NB; ++b) {
            int vS = partS[t * NB + b]; partS[t * NB + b] = runS; runS += vS;
            int vD = partD[t * NB + b]; partD[t * NB + b] = runD; runD += vD;
        }
    }
    if (t == 0) { sOff[NBK] = E; dOff[NBK] = E; eoff[N] = E; }
}

// Pass B: place edges using per-block LDS cursors seeded with absolute bases. No global atomics.
__global__ __launch_bounds__(256) void k_bucketB2(const int* __restrict__ src,
                                                  const int* __restrict__ dst,
                                                  const int* __restrict__ partS,
                                                  const int* __restrict__ partD,
                                                  unsigned int* __restrict__ dpairs,
                                                  unsigned char* __restrict__ sloc,
                                                  int E, int NBK) {
    __shared__ int cS[512], cD[512];
    int b = blockIdx.x, t = threadIdx.x;
    for (int j = t; j < NBK; j += 256) {
        cS[j] = partS[j * NB + b];
        cD[j] = partD[j * NB + b];
    }
    __syncthreads();
    int chunk = (E + NB - 1) / NB;
    int e0 = b * chunk, e1 = min(E, e0 + chunk);
    for (int e = e0 + t; e < e1; e += 256) {
        int s = src[e], d = dst[e];
        int pD = atomicAdd(&cD[d >> 8], 1);
        dpairs[pD] = ((unsigned int)(d & 255) << 17) | (unsigned int)s;
        int pS = atomicAdd(&cS[s >> 8], 1);
        sloc[pS] = (unsigned char)(s & 255);
    }
}

// Pass C: per dst-bucket: fine histogram -> nd + eoff, then place esrc via LDS cursors.
__global__ __launch_bounds__(256) void k_bucketC(const unsigned int* __restrict__ dpairs,
                                                 const int* __restrict__ dOff,
                                                 int* __restrict__ eoff,
                                                 int* __restrict__ esrc,
                                                 float* __restrict__ nd,
                                                 int N) {
    __shared__ int hist[256], sc[256], cur[256];
    int b = blockIdx.x, t = threadIdx.x;
    int base = dOff[b], end = dOff[b + 1];
    hist[t] = 0;
    __syncthreads();
    for (int i = base + t; i < end; i += 256)
        atomicAdd(&hist[dpairs[i] >> 17], 1);
    __syncthreads();
    int cnt = hist[t];
    int v = b * 256 + t;
    if (v < N) nd[v] = rsqrtf((float)max(cnt, 1));
    sc[t] = cnt;
    __syncthreads();
    for (int o = 1; o < 256; o <<= 1) {
        int x = (t >= o) ? sc[t - o] : 0;
        __syncthreads();
        sc[t] += x;
        __syncthreads();
    }
    int excl = sc[t] - cnt;
    if (v < N) eoff[v] = base + excl;
    cur[t] = excl;
    __syncthreads();
    for (int i = base + t; i < end; i += 256) {
        unsigned int pk = dpairs[i];
        int pos = atomicAdd(&cur[pk >> 17], 1);
        esrc[base + pos] = (int)(pk & 0x1FFFFu);
    }
}

// Pass C': per src-bucket: fine histogram -> ns.
__global__ __launch_bounds__(256) void k_bucketCs(const unsigned char* __restrict__ sloc,
                                                  const int* __restrict__ sOff,
                                                  float* __restrict__ ns,
                                                  int N) {
    __shared__ int hist[256];
    int b = blockIdx.x, t = threadIdx.x;
    int base = sOff[b], end = sOff[b + 1];
    hist[t] = 0;
    __syncthreads();
    for (int i = base + t; i < end; i += 256)
        atomicAdd(&hist[sloc[i]], 1);
    __syncthreads();
    int v = b * 256 + t;
    if (v < N) ns[v] = rsqrtf((float)max(hist[t], 1));
}

// ---------------- h pre-scale + bf16 convert: hb[v][d] = bf16(h[v][d]*ns[v]) ----------------
__global__ void k_hconv(const float* __restrict__ h, const float* __restrict__ ns,
                        unsigned short* __restrict__ hb, int total4) {
    int i = blockIdx.x * 256 + threadIdx.x;  // one float4 per thread
    if (i >= total4) return;
    int node = i >> 5;  // 32 float4 per row of 128
    float nsv = ns[node];
    float4 v = ((const float4*)h)[i];
    ushort4 o;
    o.x = f2bf(v.x * nsv);
    o.y = f2bf(v.y * nsv);
    o.z = f2bf(v.z * nsv);
    o.w = f2bf(v.w * nsv);
    ((ushort4*)hb)[i] = o;
}

// ---------------- W prep: transpose + bf16 ----------------
__global__ void k_wprep(const float* __restrict__ W1, const float* __restrict__ W2,
                        unsigned short* __restrict__ Wt1, unsigned short* __restrict__ Wt2) {
    int t = blockIdx.x * 256 + threadIdx.x;
    if (t < IN_DIM * HID) {
        int k = t & (IN_DIM - 1), n = t >> 7;
        Wt1[(size_t)n * IN_DIM + k] = f2bf(W1[(size_t)k * HID + n]);
    }
    if (t < HID * OUTD) {
        int k = t & (HID - 1), n = t >> 8;
        Wt2[(size_t)n * HID + k] = f2bf(W2[(size_t)k * OUTD + n]);
    }
}

// ---------------- SPMM1: bf16 gather of hb (pre-scaled), out xb bf16 [N][128] ----------------
__global__ __launch_bounds__(256) void k_spmm1(const unsigned short* __restrict__ hb,
                                               const int* __restrict__ eoff,
                                               const int* __restrict__ esrc,
                                               const float* __restrict__ nd,
                                               unsigned short* __restrict__ xb, int N) {
    int wid = threadIdx.x >> 6;
    int v = blockIdx.x * 4 + wid;
    if (v >= N) return;
    int l = threadIdx.x & 63;
    int c = l & 15, el = l >> 4;
    int s0 = eoff[v], s1 = eoff[v + 1];

    float a0[8] = {0.f, 0.f, 0.f, 0.f, 0.f, 0.f, 0.f, 0.f};
    float a1[8] = {0.f, 0.f, 0.f, 0.f, 0.f, 0.f, 0.f, 0.f};
    int i = s0 + el;
    for (; i + 4 < s1; i += 8) {
        int sA = esrc[i], sB = esrc[i + 4];
        ushort8v uA = *(const ushort8v*)(hb + (size_t)sA * IN_DIM + c * 8);
        ushort8v uB = *(const ushort8v*)(hb + (size_t)sB * IN_DIM + c * 8);
#pragma unroll
        for (int k = 0; k < 8; ++k) {
            a0[k] += bf2f((unsigned short)uA[k]);
            a1[k] += bf2f((unsigned short)uB[k]);
        }
    }
    for (; i < s1; i += 4) {
        int sA = esrc[i];
        ushort8v uA = *(const ushort8v*)(hb + (size_t)sA * IN_DIM + c * 8);
#pragma unroll
        for (int k = 0; k < 8; ++k) a0[k] += bf2f((unsigned short)uA[k]);
    }
    float s[8];
#pragma unroll
    for (int k = 0; k < 8; ++k) {
        float x = a0[k] + a1[k];
        x += __shfl_xor(x, 16);
        x += __shfl_xor(x, 32);
        s[k] = x;
    }
    if (el == 0) {
        float ndv = nd[v];
        uint4 o;
        unsigned int* op = (unsigned int*)&o;
#pragma unroll
        for (int k = 0; k < 4; ++k) {
            unsigned int lo = f2bf(s[2 * k] * ndv);
            unsigned int hi = f2bf(s[2 * k + 1] * ndv);
            op[k] = lo | (hi << 16);
        }
        *(uint4*)(xb + (size_t)v * IN_DIM + c * 8) = o;
    }
}

// ---------------- MFMA GEMM: C = A(M x K,bf16) * Bt(BN x K,bf16)^T ----------------
template <int EPI>
__global__ __launch_bounds__(256) void k_mgemm(const unsigned short* __restrict__ A,
                                               const unsigned short* __restrict__ Bt,
                                               const float* __restrict__ b1,
                                               const float* __restrict__ p,
                                               const float* __restrict__ ns,
                                               unsigned short* __restrict__ outp,
                                               int M) {
    constexpr int BM = (EPI == 1) ? 64 : 256;
    constexpr int BN = (EPI == 1) ? 256 : 64;
    constexpr int K = (EPI == 1) ? 128 : 256;
    constexpr int OUT_LD = (EPI == 1) ? 256 : 64;
    __shared__ unsigned short As[BM * 64];
    __shared__ unsigned short Bs[BN * 64];
    const int t = threadIdx.x, w = t >> 6, l = t & 63;
    const int row0 = blockIdx.x * BM;
    const int wm0 = (EPI == 1) ? 0 : w * 64;
    const int wn0 = (EPI == 1) ? w * 64 : 0;
    const int lr = l & 15, lk = (l >> 4) * 8, lg = l >> 4;

    f32x4 acc[4][4] = {};

    for (int k0 = 0; k0 < K; k0 += 64) {
#pragma unroll
        for (int q = 0; q < BM / 32; ++q) {
            int chunk = w * (BM / 32) + q;
            int gr = row0 + chunk * 8 + (l >> 3);
            if (gr > M - 1) gr = M - 1;
            const unsigned short* gp = A + (size_t)gr * K + k0 + (l & 7) * 8;
            __builtin_amdgcn_global_load_lds((const __attribute__((address_space(1))) void*)gp,
                                             (__attribute__((address_space(3))) void*)&As[chunk * 512], 16, 0, 0);
        }
#pragma unroll
        for (int q = 0; q < BN / 32; ++q) {
            int chunk = w * (BN / 32) + q;
            int r = chunk * 8 + (l >> 3);
            const unsigned short* gp = Bt + (size_t)r * K + k0 + (l & 7) * 8;
            __builtin_amdgcn_global_load_lds((const __attribute__((address_space(1))) void*)gp,
                                             (__attribute__((address_space(3))) void*)&Bs[chunk * 512], 16, 0, 0);
        }
        __syncthreads();

#pragma unroll
        for (int kk = 0; kk < 2; ++kk) {
            bf16x8 a[4], b[4];
#pragma unroll
            for (int m = 0; m < 4; ++m)
                a[m] = *(const bf16x8*)&As[(wm0 + m * 16 + lr) * 64 + kk * 32 + lk];
#pragma unroll
            for (int n = 0; n < 4; ++n)
                b[n] = *(const bf16x8*)&Bs[(wn0 + n * 16 + lr) * 64 + kk * 32 + lk];
#pragma unroll
            for (int m = 0; m < 4; ++m)
#pragma unroll
                for (int n = 0; n < 4; ++n)
                    acc[m][n] = __builtin_amdgcn_mfma_f32_16x16x32_bf16(a[m], b[n], acc[m][n], 0, 0, 0);
        }
        __syncthreads();
    }

#pragma unroll
    for (int n = 0; n < 4; ++n) {
        int col = wn0 + n * 16 + lr;
        float bb = 0.f, pp = 1.f;
        if (EPI == 1) {
            bb = b1[col];
            pp = fminf(fmaxf(p[col], 0.f), 1.f);
        }
#pragma unroll
        for (int m = 0; m < 4; ++m) {
#pragma unroll
            for (int j = 0; j < 4; ++j) {
                int row = row0 + wm0 + m * 16 + lg * 4 + j;
                if (row < M) {
                    float v = acc[m][n][j];
                    if (EPI == 1) {
                        v = fmaxf(v + bb, 0.f) * pp;
                    } else {
                        v *= ns[row];
                    }
                    outp[(size_t)row * OUT_LD + col] = f2bf(v);
                }
            }
        }
    }
}

// ---------------- SPMM2: bf16 gather of y, out fp32 ----------------
__global__ __launch_bounds__(256) void k_spmm2(const unsigned short* __restrict__ ybf,
                                               const int* __restrict__ eoff,
                                               const int* __restrict__ esrc,
                                               const float* __restrict__ nd,
                                               const float* __restrict__ b2,
                                               float* __restrict__ out, int N) {
    int wid = threadIdx.x >> 6;
    int v = blockIdx.x * 4 + wid;
    if (v >= N) return;
    int l = threadIdx.x & 63;
    int c = l & 15, el = l >> 4;
    int s0 = eoff[v], s1 = eoff[v + 1];

    float ax0 = 0.f, ay0 = 0.f, az0 = 0.f, aw0 = 0.f;
    float ax1 = 0.f, ay1 = 0.f, az1 = 0.f, aw1 = 0.f;
    int i = s0 + el;
    for (; i + 4 < s1; i += 8) {
        int sA = esrc[i], sB = esrc[i + 4];
        ushort4 uA = *(const ushort4*)(ybf + (size_t)sA * OUTD + c * 4);
        ushort4 uB = *(const ushort4*)(ybf + (size_t)sB * OUTD + c * 4);
        ax0 += bf2f(uA.x); ay0 += bf2f(uA.y); az0 += bf2f(uA.z); aw0 += bf2f(uA.w);
        ax1 += bf2f(uB.x); ay1 += bf2f(uB.y); az1 += bf2f(uB.z); aw1 += bf2f(uB.w);
    }
    for (; i < s1; i += 4) {
        ushort4 u = *(const ushort4*)(ybf + (size_t)esrc[i] * OUTD + c * 4);
        ax0 += bf2f(u.x); ay0 += bf2f(u.y); az0 += bf2f(u.z); aw0 += bf2f(u.w);
    }
    float ax = ax0 + ax1, ay = ay0 + ay1, az = az0 + az1, aw = aw0 + aw1;
    ax += __shfl_xor(ax, 16); ax += __shfl_xor(ax, 32);
    ay += __shfl_xor(ay, 16); ay += __shfl_xor(ay, 32);
    az += __shfl_xor(az, 16); az += __shfl_xor(az, 32);
    aw += __shfl_xor(aw, 16); aw += __shfl_xor(aw, 32);
    if (l < 16) {
        float ndv = nd[v];
        float4 bb = *(const float4*)(b2 + c * 4);
        float4 o;
        o.x = ax * ndv + bb.x;
        o.y = ay * ndv + bb.y;
        o.z = az * ndv + bb.z;
        o.w = aw * ndv + bb.w;
        *(float4*)(out + (size_t)v * OUTD + c * 4) = o;
    }
}

extern "C" void kernel_launch(void* const* d_in, const int* in_sizes, int n_in,
                              void* d_out, int out_size, void* d_ws, size_t ws_size,
                              hipStream_t stream) {
    const float* h  = (const float*)d_in[0];
    const float* W1 = (const float*)d_in[1];
    const float* b1 = (const float*)d_in[2];
    const float* W2 = (const float*)d_in[3];
    const float* b2 = (const float*)d_in[4];
    const float* p  = (const float*)d_in[5];
    const int* src  = (const int*)d_in[6];
    const int* dst  = (const int*)d_in[7];

    const int N = in_sizes[0] / IN_DIM;
    const int E = in_sizes[6];
    const int NBK = (N + 255) >> 8;  // 391 for N=100000 (<= 512)
    float* out = (float*)d_out;

    char* ws = (char*)d_ws;
    size_t off = 0;
    auto alloc = [&](size_t bytes) -> void* {
        void* ptr = ws + off;
        off = (off + bytes + 255) & ~(size_t)255;
        return ptr;
    };
    int* sOff = (int*)alloc(513 * 4);
    int* dOff = (int*)alloc(513 * 4);
    int* eoff = (int*)alloc((size_t)(N + 1) * 4);
    int* esrc = (int*)alloc((size_t)E * 4);
    float* ns = (float*)alloc((size_t)N * 4);
    float* nd = (float*)alloc((size_t)N * 4);
    unsigned short* hb  = (unsigned short*)alloc((size_t)N * IN_DIM * 2);  // 25.6 MB
    unsigned short* xb  = (unsigned short*)alloc((size_t)N * IN_DIM * 2);  // 25.6 MB
    unsigned short* hid = (unsigned short*)alloc((size_t)N * HID * 2);     // 51.2 MB
    unsigned short* Wt1 = (unsigned short*)alloc((size_t)HID * IN_DIM * 2);
    unsigned short* Wt2 = (unsigned short*)alloc((size_t)OUTD * HID * 2);
    unsigned short* ybf = xb;  // xb dead after GEMM1
    // build-time overlays in the hid region (dead until GEMM1 writes it)
    unsigned int* dpairs = (unsigned int*)hid;                             // E*4 = 6.4 MB
    unsigned char* sloc  = (unsigned char*)hid + (size_t)E * 4;            // E*1 = 1.6 MB
    int* partS = (int*)((char*)hid + ((size_t)E * 5 + 255 & ~(size_t)255)); // 512KB
    int* partD = partS + 512 * NB;                                          // 512KB

    int tpb = 256;
    k_bucketA<<<NB, 256, 0, stream>>>(src, dst, partS, partD, E, NBK);
    k_bscan2<<<1, 512, 0, stream>>>(partS, partD, sOff, dOff, eoff, N, E, NBK);
    k_bucketB2<<<NB, 256, 0, stream>>>(src, dst, partS, partD, dpairs, sloc, E, NBK);
    k_bucketC<<<NBK, 256, 0, stream>>>(dpairs, dOff, eoff, esrc, nd, N);
    k_bucketCs<<<NBK, 256, 0, stream>>>(sloc, sOff, ns, N);

    int total4 = N * (IN_DIM / 4);
    k_hconv<<<(total4 + tpb - 1) / tpb, tpb, 0, stream>>>(h, ns, hb, total4);

    k_wprep<<<(IN_DIM * HID + 255) / 256, 256, 0, stream>>>(W1, W2, Wt1, Wt2);

    k_spmm1<<<(N + 3) / 4, 256, 0, stream>>>(hb, eoff, esrc, nd, xb, N);

    k_mgemm<1><<<(N + 63) / 64, 256, 0, stream>>>(xb, Wt1, b1, p, nullptr, hid, N);

    k_mgemm<2><<<(N + 255) / 256, 256, 0, stream>>>(hid, Wt2, nullptr, nullptr, ns, ybf, N);

    k_spmm2<<<(N + 3) / 4, 256, 0, stream>>>(ybf, eoff, esrc, nd, b2, out, N);
}

// Round 8
// 348.857 us; speedup vs baseline: 2.8706x; 1.2227x over previous
//
#include <hip/hip_runtime.h>

#define IN_DIM 128
#define HID 256
#define OUTD 64
#define NB 256  // build blocks

typedef __attribute__((ext_vector_type(8))) short bf16x8;
typedef __attribute__((ext_vector_type(4))) float f32x4;
typedef __attribute__((ext_vector_type(8))) unsigned short ushort8v;

// ---- bf16 helpers (RNE) ----
__device__ __forceinline__ unsigned short f2bf(float x) {
    unsigned int u = __float_as_uint(x);
    unsigned int r = (u + 0x7fffu + ((u >> 16) & 1u)) >> 16;
    return (unsigned short)r;
}
__device__ __forceinline__ float bf2f(unsigned short b) {
    return __uint_as_float(((unsigned int)b) << 16);
}

// ================= atomic-chain-free bucket-sort CSR build =================
// Buckets of 256 nodes: bucket(v) = v>>8. NBK = ceil(N/256) <= 512.
// part arrays layout: part[bucket * NB + block].

// Pass A: per-block LDS histograms over a chunk, written non-atomically.
__global__ __launch_bounds__(256) void k_bucketA(const int* __restrict__ src,
                                                 const int* __restrict__ dst,
                                                 int* __restrict__ partS, int* __restrict__ partD,
                                                 int E, int NBK) {
    __shared__ int hS[512], hD[512];
    int b = blockIdx.x, t = threadIdx.x;
    for (int j = t; j < 512; j += 256) { hS[j] = 0; hD[j] = 0; }
    __syncthreads();
    int chunk = (E + NB - 1) / NB;
    int e0 = b * chunk, e1 = min(E, e0 + chunk);
    for (int e = e0 + t; e < e1; e += 256) {
        atomicAdd(&hS[src[e] >> 8], 1);
        atomicAdd(&hD[dst[e] >> 8], 1);
    }
    __syncthreads();
    for (int j = t; j < NBK; j += 256) {
        partS[j * NB + b] = hS[j];
        partD[j * NB + b] = hD[j];
    }
}

// Per-bucket parallel scan: exclusive relative prefix over the NB=256 per-block counts (in place),
// bucket totals out. One block per bucket.
__global__ __launch_bounds__(256) void k_bscanP(int* __restrict__ partS, int* __restrict__ partD,
                                                int* __restrict__ totS, int* __restrict__ totD) {
    __shared__ int sS[256], sD[256];
    int j = blockIdx.x, t = threadIdx.x;
    int vS = partS[j * NB + t], vD = partD[j * NB + t];
    sS[t] = vS; sD[t] = vD;
    __syncthreads();
    for (int o = 1; o < 256; o <<= 1) {
        int xS = (t >= o) ? sS[t - o] : 0;
        int xD = (t >= o) ? sD[t - o] : 0;
        __syncthreads();
        sS[t] += xS; sD[t] += xD;
        __syncthreads();
    }
    partS[j * NB + t] = sS[t] - vS;  // exclusive, bucket-relative
    partD[j * NB + t] = sD[t] - vD;
    if (t == 255) { totS[j] = sS[255]; totD[j] = sD[255]; }
}

// One-block scan over bucket totals only -> absolute bucket offsets.
__global__ __launch_bounds__(512) void k_bscanT(const int* __restrict__ totS,
                                                const int* __restrict__ totD,
                                                int* __restrict__ sOff, int* __restrict__ dOff,
                                                int* __restrict__ eoff,
                                                int N, int E, int NBK) {
    __shared__ int sS[512], sD[512];
    int t = threadIdx.x;
    int vS = (t < NBK) ? totS[t] : 0;
    int vD = (t < NBK) ? totD[t] : 0;
    sS[t] = vS; sD[t] = vD;
    __syncthreads();
    for (int o = 1; o < 512; o <<= 1) {
        int xS = (t >= o) ? sS[t - o] : 0;
        int xD = (t >= o) ? sD[t - o] : 0;
        __syncthreads();
        sS[t] += xS; sD[t] += xD;
        __syncthreads();
    }
    if (t < NBK) { sOff[t] = sS[t] - vS; dOff[t] = sD[t] - vD; }
    if (t == 0) { sOff[NBK] = E; dOff[NBK] = E; eoff[N] = E; }
}

// Pass B: place edges using per-block LDS cursors = relative prefix + bucket base. No global atomics.
__global__ __launch_bounds__(256) void k_bucketB2(const int* __restrict__ src,
                                                  const int* __restrict__ dst,
                                                  const int* __restrict__ partS,
                                                  const int* __restrict__ partD,
                                                  const int* __restrict__ sOff,
                                                  const int* __restrict__ dOff,
                                                  unsigned int* __restrict__ dpairs,
                                                  unsigned char* __restrict__ sloc,
                                                  int E, int NBK) {
    __shared__ int cS[512], cD[512];
    int b = blockIdx.x, t = threadIdx.x;
    for (int j = t; j < NBK; j += 256) {
        cS[j] = partS[j * NB + b] + sOff[j];
        cD[j] = partD[j * NB + b] + dOff[j];
    }
    __syncthreads();
    int chunk = (E + NB - 1) / NB;
    int e0 = b * chunk, e1 = min(E, e0 + chunk);
    for (int e = e0 + t; e < e1; e += 256) {
        int s = src[e], d = dst[e];
        int pD = atomicAdd(&cD[d >> 8], 1);
        dpairs[pD] = ((unsigned int)(d & 255) << 17) | (unsigned int)s;
        int pS = atomicAdd(&cS[s >> 8], 1);
        sloc[pS] = (unsigned char)(s & 255);
    }
}

// Pass C: per dst-bucket: fine histogram -> nd + eoff, then place esrc via LDS cursors.
__global__ __launch_bounds__(256) void k_bucketC(const unsigned int* __restrict__ dpairs,
                                                 const int* __restrict__ dOff,
                                                 int* __restrict__ eoff,
                                                 int* __restrict__ esrc,
                                                 float* __restrict__ nd,
                                                 int N) {
    __shared__ int hist[256], sc[256], cur[256];
    int b = blockIdx.x, t = threadIdx.x;
    int base = dOff[b], end = dOff[b + 1];
    hist[t] = 0;
    __syncthreads();
    for (int i = base + t; i < end; i += 256)
        atomicAdd(&hist[dpairs[i] >> 17], 1);
    __syncthreads();
    int cnt = hist[t];
    int v = b * 256 + t;
    if (v < N) nd[v] = rsqrtf((float)max(cnt, 1));
    sc[t] = cnt;
    __syncthreads();
    for (int o = 1; o < 256; o <<= 1) {
        int x = (t >= o) ? sc[t - o] : 0;
        __syncthreads();
        sc[t] += x;
        __syncthreads();
    }
    int excl = sc[t] - cnt;
    if (v < N) eoff[v] = base + excl;
    cur[t] = excl;
    __syncthreads();
    for (int i = base + t; i < end; i += 256) {
        unsigned int pk = dpairs[i];
        int pos = atomicAdd(&cur[pk >> 17], 1);
        esrc[base + pos] = (int)(pk & 0x1FFFFu);
    }
}

// Pass C': per src-bucket: fine histogram -> ns.
__global__ __launch_bounds__(256) void k_bucketCs(const unsigned char* __restrict__ sloc,
                                                  const int* __restrict__ sOff,
                                                  float* __restrict__ ns,
                                                  int N) {
    __shared__ int hist[256];
    int b = blockIdx.x, t = threadIdx.x;
    int base = sOff[b], end = sOff[b + 1];
    hist[t] = 0;
    __syncthreads();
    for (int i = base + t; i < end; i += 256)
        atomicAdd(&hist[sloc[i]], 1);
    __syncthreads();
    int v = b * 256 + t;
    if (v < N) ns[v] = rsqrtf((float)max(hist[t], 1));
}

// ---------------- h pre-scale + bf16 convert: hb[v][d] = bf16(h[v][d]*ns[v]) ----------------
__global__ void k_hconv(const float* __restrict__ h, const float* __restrict__ ns,
                        unsigned short* __restrict__ hb, int total4) {
    int i = blockIdx.x * 256 + threadIdx.x;  // one float4 per thread
    if (i >= total4) return;
    int node = i >> 5;  // 32 float4 per row of 128
    float nsv = ns[node];
    float4 v = ((const float4*)h)[i];
    ushort4 o;
    o.x = f2bf(v.x * nsv);
    o.y = f2bf(v.y * nsv);
    o.z = f2bf(v.z * nsv);
    o.w = f2bf(v.w * nsv);
    ((ushort4*)hb)[i] = o;
}

// ---------------- W prep: transpose + bf16 ----------------
__global__ void k_wprep(const float* __restrict__ W1, const float* __restrict__ W2,
                        unsigned short* __restrict__ Wt1, unsigned short* __restrict__ Wt2) {
    int t = blockIdx.x * 256 + threadIdx.x;
    if (t < IN_DIM * HID) {
        int k = t & (IN_DIM - 1), n = t >> 7;
        Wt1[(size_t)n * IN_DIM + k] = f2bf(W1[(size_t)k * HID + n]);
    }
    if (t < HID * OUTD) {
        int k = t & (HID - 1), n = t >> 8;
        Wt2[(size_t)n * HID + k] = f2bf(W2[(size_t)k * OUTD + n]);
    }
}

// ---------------- SPMM1: bf16 gather of hb (pre-scaled), out xb bf16 [N][128] ----------------
__global__ __launch_bounds__(256) void k_spmm1(const unsigned short* __restrict__ hb,
                                               const int* __restrict__ eoff,
                                               const int* __restrict__ esrc,
                                               const float* __restrict__ nd,
                                               unsigned short* __restrict__ xb, int N) {
    int wid = threadIdx.x >> 6;
    int v = blockIdx.x * 4 + wid;
    if (v >= N) return;
    int l = threadIdx.x & 63;
    int c = l & 15, el = l >> 4;
    int s0 = eoff[v], s1 = eoff[v + 1];

    float a0[8] = {0.f, 0.f, 0.f, 0.f, 0.f, 0.f, 0.f, 0.f};
    float a1[8] = {0.f, 0.f, 0.f, 0.f, 0.f, 0.f, 0.f, 0.f};
    int i = s0 + el;
    for (; i + 4 < s1; i += 8) {
        int sA = esrc[i], sB = esrc[i + 4];
        ushort8v uA = *(const ushort8v*)(hb + (size_t)sA * IN_DIM + c * 8);
        ushort8v uB = *(const ushort8v*)(hb + (size_t)sB * IN_DIM + c * 8);
#pragma unroll
        for (int k = 0; k < 8; ++k) {
            a0[k] += bf2f((unsigned short)uA[k]);
            a1[k] += bf2f((unsigned short)uB[k]);
        }
    }
    for (; i < s1; i += 4) {
        int sA = esrc[i];
        ushort8v uA = *(const ushort8v*)(hb + (size_t)sA * IN_DIM + c * 8);
#pragma unroll
        for (int k = 0; k < 8; ++k) a0[k] += bf2f((unsigned short)uA[k]);
    }
    float s[8];
#pragma unroll
    for (int k = 0; k < 8; ++k) {
        float x = a0[k] + a1[k];
        x += __shfl_xor(x, 16);
        x += __shfl_xor(x, 32);
        s[k] = x;
    }
    if (el == 0) {
        float ndv = nd[v];
        uint4 o;
        unsigned int* op = (unsigned int*)&o;
#pragma unroll
        for (int k = 0; k < 4; ++k) {
            unsigned int lo = f2bf(s[2 * k] * ndv);
            unsigned int hi = f2bf(s[2 * k + 1] * ndv);
            op[k] = lo | (hi << 16);
        }
        *(uint4*)(xb + (size_t)v * IN_DIM + c * 8) = o;
    }
}

// ---------------- MFMA GEMM: C = A(M x K,bf16) * Bt(BN x K,bf16)^T ----------------
template <int EPI>
__global__ __launch_bounds__(256) void k_mgemm(const unsigned short* __restrict__ A,
                                               const unsigned short* __restrict__ Bt,
                                               const float* __restrict__ b1,
                                               const float* __restrict__ p,
                                               const float* __restrict__ ns,
                                               unsigned short* __restrict__ outp,
                                               int M) {
    constexpr int BM = (EPI == 1) ? 64 : 256;
    constexpr int BN = (EPI == 1) ? 256 : 64;
    constexpr int K = (EPI == 1) ? 128 : 256;
    constexpr int OUT_LD = (EPI == 1) ? 256 : 64;
    __shared__ unsigned short As[BM * 64];
    __shared__ unsigned short Bs[BN * 64];
    const int t = threadIdx.x, w = t >> 6, l = t & 63;
    const int row0 = blockIdx.x * BM;
    const int wm0 = (EPI == 1) ? 0 : w * 64;
    const int wn0 = (EPI == 1) ? w * 64 : 0;
    const int lr = l & 15, lk = (l >> 4) * 8, lg = l >> 4;

    f32x4 acc[4][4] = {};

    for (int k0 = 0; k0 < K; k0 += 64) {
#pragma unroll
        for (int q = 0; q < BM / 32; ++q) {
            int chunk = w * (BM / 32) + q;
            int gr = row0 + chunk * 8 + (l >> 3);
            if (gr > M - 1) gr = M - 1;
            const unsigned short* gp = A + (size_t)gr * K + k0 + (l & 7) * 8;
            __builtin_amdgcn_global_load_lds((const __attribute__((address_space(1))) void*)gp,
                                             (__attribute__((address_space(3))) void*)&As[chunk * 512], 16, 0, 0);
        }
#pragma unroll
        for (int q = 0; q < BN / 32; ++q) {
            int chunk = w * (BN / 32) + q;
            int r = chunk * 8 + (l >> 3);
            const unsigned short* gp = Bt + (size_t)r * K + k0 + (l & 7) * 8;
            __builtin_amdgcn_global_load_lds((const __attribute__((address_space(1))) void*)gp,
                                             (__attribute__((address_space(3))) void*)&Bs[chunk * 512], 16, 0, 0);
        }
        __syncthreads();

#pragma unroll
        for (int kk = 0; kk < 2; ++kk) {
            bf16x8 a[4], b[4];
#pragma unroll
            for (int m = 0; m < 4; ++m)
                a[m] = *(const bf16x8*)&As[(wm0 + m * 16 + lr) * 64 + kk * 32 + lk];
#pragma unroll
            for (int n = 0; n < 4; ++n)
                b[n] = *(const bf16x8*)&Bs[(wn0 + n * 16 + lr) * 64 + kk * 32 + lk];
#pragma unroll
            for (int m = 0; m < 4; ++m)
#pragma unroll
                for (int n = 0; n < 4; ++n)
                    acc[m][n] = __builtin_amdgcn_mfma_f32_16x16x32_bf16(a[m], b[n], acc[m][n], 0, 0, 0);
        }
        __syncthreads();
    }

#pragma unroll
    for (int n = 0; n < 4; ++n) {
        int col = wn0 + n * 16 + lr;
        float bb = 0.f, pp = 1.f;
        if (EPI == 1) {
            bb = b1[col];
            pp = fminf(fmaxf(p[col], 0.f), 1.f);
        }
#pragma unroll
        for (int m = 0; m < 4; ++m) {
#pragma unroll
            for (int j = 0; j < 4; ++j) {
                int row = row0 + wm0 + m * 16 + lg * 4 + j;
                if (row < M) {
                    float v = acc[m][n][j];
                    if (EPI == 1) {
                        v = fmaxf(v + bb, 0.f) * pp;
                    } else {
                        v *= ns[row];
                    }
                    outp[(size_t)row * OUT_LD + col] = f2bf(v);
                }
            }
        }
    }
}

// ---------------- SPMM2: bf16 gather of y, out fp32 ----------------
__global__ __launch_bounds__(256) void k_spmm2(const unsigned short* __restrict__ ybf,
                                               const int* __restrict__ eoff,
                                               const int* __restrict__ esrc,
                                               const float* __restrict__ nd,
                                               const float* __restrict__ b2,
                                               float* __restrict__ out, int N) {
    int wid = threadIdx.x >> 6;
    int v = blockIdx.x * 4 + wid;
    if (v >= N) return;
    int l = threadIdx.x & 63;
    int c = l & 15, el = l >> 4;
    int s0 = eoff[v], s1 = eoff[v + 1];

    float ax0 = 0.f, ay0 = 0.f, az0 = 0.f, aw0 = 0.f;
    float ax1 = 0.f, ay1 = 0.f, az1 = 0.f, aw1 = 0.f;
    int i = s0 + el;
    for (; i + 4 < s1; i += 8) {
        int sA = esrc[i], sB = esrc[i + 4];
        ushort4 uA = *(const ushort4*)(ybf + (size_t)sA * OUTD + c * 4);
        ushort4 uB = *(const ushort4*)(ybf + (size_t)sB * OUTD + c * 4);
        ax0 += bf2f(uA.x); ay0 += bf2f(uA.y); az0 += bf2f(uA.z); aw0 += bf2f(uA.w);
        ax1 += bf2f(uB.x); ay1 += bf2f(uB.y); az1 += bf2f(uB.z); aw1 += bf2f(uB.w);
    }
    for (; i < s1; i += 4) {
        ushort4 u = *(const ushort4*)(ybf + (size_t)esrc[i] * OUTD + c * 4);
        ax0 += bf2f(u.x); ay0 += bf2f(u.y); az0 += bf2f(u.z); aw0 += bf2f(u.w);
    }
    float ax = ax0 + ax1, ay = ay0 + ay1, az = az0 + az1, aw = aw0 + aw1;
    ax += __shfl_xor(ax, 16); ax += __shfl_xor(ax, 32);
    ay += __shfl_xor(ay, 16); ay += __shfl_xor(ay, 32);
    az += __shfl_xor(az, 16); az += __shfl_xor(az, 32);
    aw += __shfl_xor(aw, 16); aw += __shfl_xor(aw, 32);
    if (l < 16) {
        float ndv = nd[v];
        float4 bb = *(const float4*)(b2 + c * 4);
        float4 o;
        o.x = ax * ndv + bb.x;
        o.y = ay * ndv + bb.y;
        o.z = az * ndv + bb.z;
        o.w = aw * ndv + bb.w;
        *(float4*)(out + (size_t)v * OUTD + c * 4) = o;
    }
}

extern "C" void kernel_launch(void* const* d_in, const int* in_sizes, int n_in,
                              void* d_out, int out_size, void* d_ws, size_t ws_size,
                              hipStream_t stream) {
    const float* h  = (const float*)d_in[0];
    const float* W1 = (const float*)d_in[1];
    const float* b1 = (const float*)d_in[2];
    const float* W2 = (const float*)d_in[3];
    const float* b2 = (const float*)d_in[4];
    const float* p  = (const float*)d_in[5];
    const int* src  = (const int*)d_in[6];
    const int* dst  = (const int*)d_in[7];

    const int N = in_sizes[0] / IN_DIM;
    const int E = in_sizes[6];
    const int NBK = (N + 255) >> 8;  // 391 for N=100000 (<= 512)
    float* out = (float*)d_out;

    char* ws = (char*)d_ws;
    size_t off = 0;
    auto alloc = [&](size_t bytes) -> void* {
        void* ptr = ws + off;
        off = (off + bytes + 255) & ~(size_t)255;
        return ptr;
    };
    int* sOff = (int*)alloc(513 * 4);
    int* dOff = (int*)alloc(513 * 4);
    int* totS = (int*)alloc(512 * 4);
    int* totD = (int*)alloc(512 * 4);
    int* eoff = (int*)alloc((size_t)(N + 1) * 4);
    int* esrc = (int*)alloc((size_t)E * 4);
    float* ns = (float*)alloc((size_t)N * 4);
    float* nd = (float*)alloc((size_t)N * 4);
    unsigned short* hb  = (unsigned short*)alloc((size_t)N * IN_DIM * 2);  // 25.6 MB
    unsigned short* xb  = (unsigned short*)alloc((size_t)N * IN_DIM * 2);  // 25.6 MB
    unsigned short* hid = (unsigned short*)alloc((size_t)N * HID * 2);     // 51.2 MB
    unsigned short* Wt1 = (unsigned short*)alloc((size_t)HID * IN_DIM * 2);
    unsigned short* Wt2 = (unsigned short*)alloc((size_t)OUTD * HID * 2);
    unsigned short* ybf = xb;  // xb dead after GEMM1
    // build-time overlays in the hid region (dead until GEMM1 writes it)
    unsigned int* dpairs = (unsigned int*)hid;                             // E*4 = 6.4 MB
    unsigned char* sloc  = (unsigned char*)hid + (size_t)E * 4;            // E*1 = 1.6 MB
    int* partS = (int*)((char*)hid + ((size_t)E * 5 + 255 & ~(size_t)255)); // 512KB
    int* partD = partS + 512 * NB;                                          // 512KB

    int tpb = 256;
    k_bucketA<<<NB, 256, 0, stream>>>(src, dst, partS, partD, E, NBK);
    k_bscanP<<<NBK, 256, 0, stream>>>(partS, partD, totS, totD);
    k_bscanT<<<1, 512, 0, stream>>>(totS, totD, sOff, dOff, eoff, N, E, NBK);
    k_bucketB2<<<NB, 256, 0, stream>>>(src, dst, partS, partD, sOff, dOff, dpairs, sloc, E, NBK);
    k_bucketC<<<NBK, 256, 0, stream>>>(dpairs, dOff, eoff, esrc, nd, N);
    k_bucketCs<<<NBK, 256, 0, stream>>>(sloc, sOff, ns, N);

    int total4 = N * (IN_DIM / 4);
    k_hconv<<<(total4 + tpb - 1) / tpb, tpb, 0, stream>>>(h, ns, hb, total4);

    k_wprep<<<(IN_DIM * HID + 255) / 256, 256, 0, stream>>>(W1, W2, Wt1, Wt2);

    k_spmm1<<<(N + 3) / 4, 256, 0, stream>>>(hb, eoff, esrc, nd, xb, N);

    k_mgemm<1><<<(N + 63) / 64, 256, 0, stream>>>(xb, Wt1, b1, p, nullptr, hid, N);

    k_mgemm<2><<<(N + 255) / 256, 256, 0, stream>>>(hid, Wt2, nullptr, nullptr, ns, ybf, N);

    k_spmm2<<<(N + 3) / 4, 256, 0, stream>>>(ybf, eoff, esrc, nd, b2, out, N);
}